// Round 14
// baseline (2256.643 us; speedup 1.0000x reference)
//
#include <hip/hip_runtime.h>

#define B_ 64
#define T_ 512
#define D_ 512
#define N_ 1024
#define G_ 4096   // 4*N

typedef _Float16 f16;
typedef __attribute__((ext_vector_type(8))) _Float16 f16x8;
typedef __attribute__((ext_vector_type(4))) _Float16 f16x4;
typedef __attribute__((ext_vector_type(4))) float f32x4_t;
typedef unsigned long long u64;

static __device__ __forceinline__ f32x4_t mfma16(f16x8 a, f16x8 b, f32x4_t c) {
    return __builtin_amdgcn_mfma_f32_16x16x32_f16(a, b, c, 0, 0, 0);
}

static __device__ __forceinline__ float fsig(float x) {
    return 1.f / (1.f + __expf(-x));
}
static __device__ __forceinline__ float ftanh(float x) {
    return 1.f - 2.f / (__expf(2.f * x) + 1.f);
}

static __device__ __forceinline__ void lds_barrier() {
    asm volatile("s_waitcnt lgkmcnt(0)" ::: "memory");
    __builtin_amdgcn_s_barrier();
    __builtin_amdgcn_sched_barrier(0);
}

// workspace map (inside first 4MB, overlapping dead WxT)
#define PAYB   131072        // one payload copy: [bg4][32KB]
#define OFF_TAG 0x60000      // 3*PAYB; tags: 4*256 u32 = 4KB

// ---------------------------------------------------------------------------
// Phase 0: WxT[g][d] = (f16) W[d][g]   (validated R1)
// ---------------------------------------------------------------------------
__global__ __launch_bounds__(256) void k_transpose_wx(const float* __restrict__ W,
                                                      f16* __restrict__ WxT) {
    __shared__ float tile[64][65];
    int bx = blockIdx.x;
    int dt = bx >> 6, gt = bx & 63;
    int d0 = dt * 64, g0 = gt * 64;
    int tid = threadIdx.x;
    for (int e = tid; e < 4096; e += 256) {
        int r = e >> 6, c = e & 63;
        tile[r][c] = W[(size_t)(d0 + r) * G_ + (g0 + c)];
    }
    __syncthreads();
    for (int e = tid; e < 4096; e += 256) {
        int r = e >> 6, c = e & 63;
        WxT[(size_t)(g0 + r) * D_ + (d0 + c)] = (f16)tile[c][r];
    }
}

// ---------------------------------------------------------------------------
// Phase 1: xp[t][g][b] = (f16)( x@Wx + bias )   (validated R1)
// ---------------------------------------------------------------------------
__global__ __launch_bounds__(256, 2) void k_xproj(const float* __restrict__ x,
                                                  const f16* __restrict__ WxT,
                                                  const float* __restrict__ bias,
                                                  f16* __restrict__ xp) {
    __shared__ __align__(16) f16 alds[64 * 512];   // 64 KB
    int t = blockIdx.x;
    int tid = threadIdx.x;
    int w = tid >> 6, l = tid & 63;

    for (int ch = tid; ch < 4096; ch += 256) {
        int b  = ch >> 6;
        int d0 = (ch & 63) << 3;
        const float* px = x + ((size_t)b * T_ + t) * D_ + d0;
        float4 v0 = *(const float4*)px;
        float4 v1 = *(const float4*)(px + 4);
        f16x8 s;
        s[0] = (f16)v0.x; s[1] = (f16)v0.y; s[2] = (f16)v0.z; s[3] = (f16)v0.w;
        s[4] = (f16)v1.x; s[5] = (f16)v1.y; s[6] = (f16)v1.z; s[7] = (f16)v1.w;
        unsigned byteoff = ((unsigned)(b * 512 + d0) * 2u) ^ ((unsigned)(b & 7) << 4);
        *(f16x8*)((char*)alds + byteoff) = s;
    }
    __syncthreads();

    const int gw = w * 1024;
    const int qk = (l >> 4) << 3;
    const int cc = l & 15;

    for (int gtb = 0; gtb < 16; ++gtb) {
        f32x4_t acc[4][4];
        #pragma unroll
        for (int a = 0; a < 4; ++a)
            #pragma unroll
            for (int m = 0; m < 4; ++m) acc[a][m] = f32x4_t{0.f, 0.f, 0.f, 0.f};

        for (int ks = 0; ks < 16; ++ks) {
            f16x8 afr[4];
            #pragma unroll
            for (int mb = 0; mb < 4; ++mb) {
                int b = mb * 16 + cc;
                int d = ks * 32 + qk;
                unsigned byteoff = ((unsigned)(b * 512 + d) * 2u) ^ ((unsigned)(b & 7) << 4);
                afr[mb] = *(const f16x8*)((const char*)alds + byteoff);
            }
            #pragma unroll
            for (int gl = 0; gl < 4; ++gl) {
                int g = gw + (gtb * 4 + gl) * 16 + cc;
                f16x8 bfr = *(const f16x8*)(WxT + (size_t)g * D_ + ks * 32 + qk);
                #pragma unroll
                for (int mb = 0; mb < 4; ++mb)
                    acc[gl][mb] = mfma16(afr[mb], bfr, acc[gl][mb]);
            }
        }
        #pragma unroll
        for (int gl = 0; gl < 4; ++gl) {
            int g = gw + (gtb * 4 + gl) * 16 + cc;
            float bg = bias[g];
            #pragma unroll
            for (int mb = 0; mb < 4; ++mb) {
                int b0 = mb * 16 + ((l >> 4) << 2);
                f16x4 sv;
                sv[0] = (f16)(acc[gl][mb][0] + bg);
                sv[1] = (f16)(acc[gl][mb][1] + bg);
                sv[2] = (f16)(acc[gl][mb][2] + bg);
                sv[3] = (f16)(acc[gl][mb][3] + bg);
                *(f16x4*)(xp + ((size_t)t * G_ + g) * B_ + b0) = sv;
            }
        }
    }
}

// ---------------------------------------------------------------------------
// Phase 2: R14 — halved fan-in. 128 WGs x 512 threads (8 waves), 1 WG/CU.
// WG (bg = wg>>5, cj = wg&31): batches [16bg,+16) x h-cols [32cj,+32).
// Wave w: k in [128w,+128) (4 kk-steps) x all 8 n-tiles = 32 MFMAs (same
// per-wave work as R10). Consumer tag fan-in: 32 (was 64); h-broadcast
// 1MB/step/bg (was 2MB). Protocol (payload -> vmcnt ack -> wave tag),
// slot layout, pack code: BIT-IDENTICAL to R10/R13.
// xp prefetched ONE STEP AHEAD (issued after publish-ack -> HBM tail off
// the serial chain). Out store deferred one step (R13).
// ---------------------------------------------------------------------------
__global__ __launch_bounds__(512, 1) void k_recur14(const float* __restrict__ W,
                                                    const f16* __restrict__ xp,
                                                    char* __restrict__ wsb,
                                                    float* __restrict__ out) {
    __shared__ float pacc[8][8][16][17];   // [kwave][ntile][batch][c15+pad] 70KB

    const int wg  = blockIdx.x;
    const int tid = threadIdx.x;
    const int w   = tid >> 6;       // 0..7
    const int l   = tid & 63;
    const int bg  = wg >> 5;        // 0..3
    const int cj  = wg & 31;        // 0..31

    const int lb    = l & 15;
    const int dh    = l >> 4;       // 0..3
    const int nh    = cj * 32 + w * 4 + dh;   // this thread's h column
    const int bglob = bg * 16 + lb;

    char*     const pay  = wsb;                      // 3 x 128 KB
    unsigned* const tags = (unsigned*)(wsb + OFF_TAG);

    // ---- Wh B-fragments: 8 n-tiles x 4 kk-steps (128 VGPR) ----
    f16x8 bf[8][4];
    {
        const int kq = l >> 4, ty = (l >> 2) & 3, dcl = l & 3;
        #pragma unroll
        for (int nt = 0; nt < 8; ++nt) {
            const int gc = ty * 1024 + cj * 32 + nt * 4 + dcl;
            #pragma unroll
            for (int kk = 0; kk < 4; ++kk) {
                #pragma unroll
                for (int i = 0; i < 8; ++i) {
                    int k = (w * 4 + kk) * 32 + kq * 8 + i;
                    bf[nt][kk][i] = (f16)W[(size_t)(D_ + k) * G_ + gc];
                }
            }
        }
    }

    // ---- producer slot addressing (same 8B-pack as R10; derived for 512t) ----
    // nh = cj*32 + w*4 + dh:  ks_h = cj,  lane_h = ((w>>1)<<4)|lb,
    // i_h = (w&1)*4 + dh  -> 4 dh values share one 8B half-slot.
    const size_t st_off = (size_t)bg * 32768
                        + ((size_t)(cj * 64 + (((w >> 1) & 3) << 4) + lb) << 4)
                        + (size_t)(w & 1) * 8;
    const bool do_st = (dh == 0);

    // ---- consumer addressing: wave w reads k-steps [4w, 4w+4) ----
    const size_t ld_off = (size_t)bg * 32768 + ((size_t)(w * 4 * 64 + l) << 4);

    // tags: producer wave (cj,w) -> index cj*8+w; consumer wave w needs
    // producer WGs cj' in [4w,4w+4) x all 8 waves = contiguous [32w, 32w+32).
    unsigned* const tag_st = tags + (bg * 256 + cj * 8 + w);
    unsigned* const tag_ld = tags + (bg * 256 + w * 32 + (l & 31));

    // ---- init: zero payload buf0 (h_0 = 0), release, tag = 1 ----
    if (do_st)
        __hip_atomic_store((u64*)(pay + st_off), 0ull,
                           __ATOMIC_RELAXED, __HIP_MEMORY_SCOPE_AGENT);
    asm volatile("s_waitcnt vmcnt(0)" ::: "memory");
    if (l == 0)
        __hip_atomic_store(tag_st, 1u, __ATOMIC_RELAXED, __HIP_MEMORY_SCOPE_AGENT);

    __syncthreads();

    // xp pointers + prologue prefetch for t=0
    const unsigned short* const xpb = (const unsigned short*)xp + bglob;
    f16 xg0, xg1, xg2, xg3;
    {
        const unsigned short* p0 = xpb + (size_t)0 * G_ * B_;
        xg0 = __builtin_bit_cast(f16, __builtin_nontemporal_load(p0 + (size_t)(0 * 1024 + nh) * B_));
        xg1 = __builtin_bit_cast(f16, __builtin_nontemporal_load(p0 + (size_t)(1 * 1024 + nh) * B_));
        xg2 = __builtin_bit_cast(f16, __builtin_nontemporal_load(p0 + (size_t)(2 * 1024 + nh) * B_));
        xg3 = __builtin_bit_cast(f16, __builtin_nontemporal_load(p0 + (size_t)(3 * 1024 + nh) * B_));
    }

    float cst = 0.f;
    int cur = 0, nxt = 1;
    float  h_prev = 0.f;
    size_t oprev  = 0;

    for (int t = 0; t < T_; ++t) {
        // deferred out store: ack overlaps this step's poll
        if (t > 0)
            __builtin_nontemporal_store(h_prev, &out[oprev]);

        // ---- poll 32 producer-wave tags (128B contiguous) ----
        {
            const unsigned tgt = (unsigned)(t + 1);
            while (true) {
                unsigned v = __hip_atomic_load(tag_ld, __ATOMIC_RELAXED,
                                               __HIP_MEMORY_SCOPE_AGENT);
                if (__all(v >= tgt)) break;
                __builtin_amdgcn_s_sleep(1);
            }
        }

        // ---- payload: 4 x 16B coherent loads ----
        f16x8 af[4];
        {
            const char* pl = pay + (size_t)cur * PAYB + ld_off;
            #pragma unroll
            for (int kk = 0; kk < 4; ++kk)
                asm volatile("global_load_dwordx4 %0, %1, off sc0 sc1"
                             : "=&v"(af[kk]) : "v"(pl + kk * 1024) : "memory");
        }
        asm volatile("s_waitcnt vmcnt(0)" ::: "memory");
        __builtin_amdgcn_sched_barrier(0);   // rule 18

        // ---- 32 MFMAs: 4 kk x 8 n-tiles ----
        f32x4_t acc[8];
        #pragma unroll
        for (int nt = 0; nt < 8; ++nt) acc[nt] = f32x4_t{0.f, 0.f, 0.f, 0.f};
        #pragma unroll
        for (int kk = 0; kk < 4; ++kk) {
            #pragma unroll
            for (int nt = 0; nt < 8; ++nt)
                acc[nt] = mfma16(af[kk], bf[nt][kk], acc[nt]);
        }

        // ---- cross-wave K-reduction via LDS (8 partials) ----
        {
            const int r0 = dh << 2;
            #pragma unroll
            for (int nt = 0; nt < 8; ++nt)
                #pragma unroll
                for (int j = 0; j < 4; ++j)
                    pacc[w][nt][r0 + j][l & 15] = acc[nt][j];
        }
        lds_barrier();

        // gate tile for this thread: ntile == w, col = ty*4+dh, row = lb
        float g0 = 0.f, g1 = 0.f, g2 = 0.f, g3 = 0.f;
        #pragma unroll
        for (int kw = 0; kw < 8; ++kw) {
            g0 += pacc[kw][w][lb][0 * 4 + dh];
            g1 += pacc[kw][w][lb][1 * 4 + dh];
            g2 += pacc[kw][w][lb][2 * 4 + dh];
            g3 += pacc[kw][w][lb][3 * 4 + dh];
        }
        g0 += (float)xg0; g1 += (float)xg1; g2 += (float)xg2; g3 += (float)xg3;

        float si = fsig(g0);
        float tj = ftanh(g1);
        float sf = fsig(g2 + 1.f);
        float so = fsig(g3);
        cst = cst * sf + si * tj;
        float h = ftanh(cst) * so;

        // ---- publish: payload stores -> wave ack -> wave tag (R10 path) ----
        {
            unsigned hu = (unsigned)__builtin_bit_cast(unsigned short, (f16)h);
            unsigned ot = __shfl_xor(hu, 16);
            unsigned dw = (dh & 1) ? ((ot & 0xffffu) | (hu << 16))
                                   : ((hu & 0xffffu) | (ot << 16));
            unsigned dw2 = __shfl_xor(dw, 32);
            if (do_st && t < T_ - 1) {
                u64 val = (u64)dw | ((u64)dw2 << 32);
                __hip_atomic_store((u64*)(pay + (size_t)nxt * PAYB + st_off), val,
                                   __ATOMIC_RELAXED, __HIP_MEMORY_SCOPE_AGENT);
            }
        }
        asm volatile("s_waitcnt vmcnt(0)" ::: "memory");   // payload acked at LLC
        if (l == 0 && t < T_ - 1)
            __hip_atomic_store(tag_st, (unsigned)(t + 2),
                               __ATOMIC_RELAXED, __HIP_MEMORY_SCOPE_AGENT);

        // ---- xp prefetch for t+1 (overlaps barrier + next poll) ----
        if (t + 1 < T_) {
            const unsigned short* pn = xpb + (size_t)(t + 1) * G_ * B_;
            xg0 = __builtin_bit_cast(f16, __builtin_nontemporal_load(pn + (size_t)(0 * 1024 + nh) * B_));
            xg1 = __builtin_bit_cast(f16, __builtin_nontemporal_load(pn + (size_t)(1 * 1024 + nh) * B_));
            xg2 = __builtin_bit_cast(f16, __builtin_nontemporal_load(pn + (size_t)(2 * 1024 + nh) * B_));
            xg3 = __builtin_bit_cast(f16, __builtin_nontemporal_load(pn + (size_t)(3 * 1024 + nh) * B_));
        }

        h_prev = h;
        oprev  = ((size_t)bglob * T_ + t) * N_ + nh;

        lds_barrier();   // pacc anti-dependency
        cur = nxt;
        nxt = (nxt == 2) ? 0 : nxt + 1;
    }
    __builtin_nontemporal_store(h_prev, &out[oprev]);
}

// ---------------------------------------------------------------------------
extern "C" void kernel_launch(void* const* d_in, const int* in_sizes, int n_in,
                              void* d_out, int out_size, void* d_ws, size_t ws_size,
                              hipStream_t stream) {
    const float* x    = (const float*)d_in[0];
    const float* W    = (const float*)d_in[1];
    const float* bias = (const float*)d_in[2];
    float* out = (float*)d_out;

    char* ws = (char*)d_ws;
    f16*  WxT = (f16*)ws;                         // [0,4MB), dead after k_xproj
    f16*  xp  = (f16*)(ws + ((size_t)4 << 20));   // 256 MB

    const size_t need = ((size_t)4 << 20) + ((size_t)1 << 28);
    if (ws_size < need) {
        hipMemsetAsync(d_out, 0, (size_t)out_size * sizeof(float), stream);
        return;
    }

    hipLaunchKernelGGL(k_transpose_wx, dim3(512), dim3(256), 0, stream, W, WxT);
    hipLaunchKernelGGL(k_xproj, dim3(512), dim3(256), 0, stream, x, WxT, bias, xp);

    // zero the tag array (region overlaps dead WxT -> must run after k_xproj);
    // re-executes on every graph replay -> deterministic protocol start.
    hipMemsetAsync(ws + OFF_TAG, 0, 4096, stream);

    const f16* xp_c = xp;
    void* args[] = { (void*)&W, (void*)&xp_c, (void*)&ws, (void*)&out };
    hipError_t e = hipLaunchCooperativeKernel((void*)k_recur14, dim3(128), dim3(512),
                                              args, 0, stream);
    if (e != hipSuccess) {
        // 70KB LDS + ~230 VGPR -> 1 WG/CU; grid 128 < 256 CUs: co-residency
        // holds under a normal launch too.
        hipLaunchKernelGGL(k_recur14, dim3(128), dim3(512), 0, stream,
                           W, xp_c, ws, out);
    }
}

// Round 15
// 1651.800 us; speedup vs baseline: 1.3662x; 1.3662x over previous
//
#include <hip/hip_runtime.h>

#define B_ 64
#define T_ 512
#define D_ 512
#define N_ 1024
#define G_ 4096   // 4*N

typedef _Float16 f16;
typedef __attribute__((ext_vector_type(8))) _Float16 f16x8;
typedef __attribute__((ext_vector_type(4))) float f32x4_t;
typedef unsigned long long u64;

static __device__ __forceinline__ f32x4_t mfma16(f16x8 a, f16x8 b, f32x4_t c) {
    return __builtin_amdgcn_mfma_f32_16x16x32_f16(a, b, c, 0, 0, 0);
}

static __device__ __forceinline__ float fsig(float x) {
    return 1.f / (1.f + __expf(-x));
}
static __device__ __forceinline__ float ftanh(float x) {
    return 1.f - 2.f / (__expf(2.f * x) + 1.f);
}

static __device__ __forceinline__ void lds_barrier() {
    asm volatile("s_waitcnt lgkmcnt(0)" ::: "memory");
    __builtin_amdgcn_s_barrier();
    __builtin_amdgcn_sched_barrier(0);
}

// workspace map: [0,4MB) protocol region; [4MB, +32MB) x-fragments
#define PAYB   131072        // one payload copy: [bg4][32KB]
#define OFF_TAG 0x60000      // 3*PAYB; tags: 4*256 u32 = 4KB
#define OFF_XF  ((size_t)4 << 20)

// ---------------------------------------------------------------------------
// Phase 0 (NEW): x -> f16 MFMA A-fragments, per (t, bg):
// xf[t][bg][ds16][lane64][i8], lane = ((d>>3)&3)*16 + (b&15), i = d&7.
// One WG per t; LDS-staged so both global sides are coalesced. ~30µs total.
// ---------------------------------------------------------------------------
__global__ __launch_bounds__(256) void k_xfrag(const float* __restrict__ x,
                                               f16* __restrict__ xf) {
    __shared__ __align__(16) f16 xl[32768];   // 64 KB
    const int t = blockIdx.x;
    const int tid = threadIdx.x;

    for (int ch = tid; ch < 4096; ch += 256) {
        int b  = ch >> 6;
        int d0 = (ch & 63) << 3;
        const float* px = x + ((size_t)b * T_ + t) * D_ + d0;
        float4 v0 = *(const float4*)px;
        float4 v1 = *(const float4*)(px + 4);
        f16x8 s;
        s[0] = (f16)v0.x; s[1] = (f16)v0.y; s[2] = (f16)v0.z; s[3] = (f16)v0.w;
        s[4] = (f16)v1.x; s[5] = (f16)v1.y; s[6] = (f16)v1.z; s[7] = (f16)v1.w;
        int bg = b >> 4, ds = d0 >> 5;
        int lane = (((d0 >> 3) & 3) << 4) | (b & 15);
        *(f16x8*)(xl + (((bg * 16 + ds) * 64 + lane) << 3)) = s;
    }
    __syncthreads();
    f16* dst = xf + (size_t)t * 32768;
    for (int j = tid; j < 4096; j += 256)
        *(f16x8*)(dst + j * 8) = *(const f16x8*)(xl + j * 8);
}

// ---------------------------------------------------------------------------
// Phase 1: persistent recurrence with x@Wx FOLDED IN (R10/R13 protocol
// verbatim). Per step per wave: 32 Wh-MFMAs (B in regs) + 16 Wx-MFMAs
// (B from 64KB LDS, A = prefetched x-fragments) -> same pacc reduce.
// Chain adds ~+150cy/step; deletes the entire 380µs xproj phase.
// ---------------------------------------------------------------------------
__global__ __launch_bounds__(256, 1) void k_recur15(const float* __restrict__ W,
                                                    const float* __restrict__ bias,
                                                    const f16* __restrict__ xf,
                                                    char* __restrict__ wsb,
                                                    float* __restrict__ out) {
    __shared__ __align__(16) f16 wx[32768];     // 64 KB Wx B-fragments
    __shared__ float pacc[4][4][16][17];        // 17.4 KB

    const int wg  = blockIdx.x;
    const int tid = threadIdx.x;
    const int w   = tid >> 6;
    const int l   = tid & 63;
    const int bg  = wg >> 6;
    const int ci  = wg & 63;

    const int lb    = l & 15;
    const int dh    = l >> 4;
    const int nh    = ci * 16 + w * 4 + dh;
    const int bglob = bg * 16 + lb;

    char*     const pay  = wsb;
    unsigned* const tags = (unsigned*)(wsb + OFF_TAG);

    // ---- Wh B-fragments into registers (validated R3/R9/R10) ----
    f16x8 bf[4][8];
    {
        const int kq = l >> 4, ty = (l >> 2) & 3, dcl = l & 3;
        #pragma unroll
        for (int nt = 0; nt < 4; ++nt) {
            const int gc = ty * 1024 + ci * 16 + nt * 4 + dcl;
            #pragma unroll
            for (int kk = 0; kk < 8; ++kk) {
                #pragma unroll
                for (int i = 0; i < 8; ++i) {
                    int k = (w * 8 + kk) * 32 + kq * 8 + i;
                    bf[nt][kk][i] = (f16)W[(size_t)(D_ + k) * G_ + gc];
                }
            }
        }
    }

    // ---- Wx B-fragments into LDS (same mapping, K = D = 512) ----
    for (int idx = tid; idx < 32768; idx += 256) {
        int gcl = idx & 63;
        int d   = idx >> 6;                     // 0..511
        int ty  = gcl >> 4, c = gcl & 15;
        float wv = W[(size_t)d * G_ + ty * 1024 + ci * 16 + c];
        int ds = d >> 5, i = d & 7, kq = (d >> 3) & 3;
        int nt = c >> 2, dcl = c & 3;
        int lane = (kq << 4) | (ty << 2) | dcl;
        wx[(((ds * 4 + nt) * 64 + lane) << 3) + i] = (f16)wv;
    }

    // bias for this thread's 4 gates
    const float b0 = bias[0 * 1024 + nh];
    const float b1 = bias[1 * 1024 + nh];
    const float b2 = bias[2 * 1024 + nh];
    const float b3 = bias[3 * 1024 + nh];

    // ---- producer/consumer addressing (R8/R10-validated) ----
    const int nq  = ci * 16 + w * 4;
    const int ksq = nq >> 5;
    const int q8  = (nq & 31) >> 3;
    const size_t st_off = (size_t)bg * 32768
                        + ((size_t)(ksq * 64 + q8 * 16 + lb) << 4)
                        + (size_t)(w & 1) * 8;
    const bool do_st = (dh == 0);
    const size_t ld_off = (size_t)bg * 32768 + ((size_t)(w * 8 * 64 + l) << 4);

    unsigned* const tag_st = tags + (bg * 256 + ci * 4 + w);
    unsigned* const tag_ld = tags + (bg * 256 + w * 64 + l);

    // x-fragment base for this (bg, wave): ds = w*4 + kk
    const f16* const xfb = xf + (size_t)bg * 16384 / 2 * 2   // bg*16384 f16
                         ;
    // (clean form below in loop: xf + t*32768 + bg*8192? -- compute directly)

    // ---- init: zero payload buf0, release, tag = 1 ----
    if (do_st)
        __hip_atomic_store((u64*)(pay + st_off), 0ull,
                           __ATOMIC_RELAXED, __HIP_MEMORY_SCOPE_AGENT);
    asm volatile("s_waitcnt vmcnt(0)" ::: "memory");
    if (l == 0)
        __hip_atomic_store(tag_st, 1u, __ATOMIC_RELAXED, __HIP_MEMORY_SCOPE_AGENT);

    __syncthreads();   // also covers wx staging

    // prologue: x-fragments for t=0 (4 x 16B plain cached loads)
    f16x8 xa[4];
    {
        const f16* p0 = xf + (size_t)bg * 8192 + ((size_t)(w * 4) * 64 + l) * 8;
        #pragma unroll
        for (int kk = 0; kk < 4; ++kk)
            xa[kk] = *(const f16x8*)(p0 + (size_t)kk * 512);
    }

    float cst = 0.f;
    int cur = 0, nxt = 1;
    float  h_prev = 0.f;
    size_t oprev  = 0;

    for (int t = 0; t < T_; ++t) {
        if (t > 0)
            __builtin_nontemporal_store(h_prev, &out[oprev]);

        // ---- poll own 64 producer-wave tags ----
        {
            const unsigned tgt = (unsigned)(t + 1);
            while (true) {
                unsigned v = __hip_atomic_load(tag_ld, __ATOMIC_RELAXED,
                                               __HIP_MEMORY_SCOPE_AGENT);
                if (__all(v >= tgt)) break;
                __builtin_amdgcn_s_sleep(1);
            }
        }

        // ---- payload: 8 x 16B coherent loads ----
        f16x8 af[8];
        {
            const char* pl = pay + (size_t)cur * PAYB + ld_off;
            #pragma unroll
            for (int kk = 0; kk < 8; ++kk)
                asm volatile("global_load_dwordx4 %0, %1, off sc0 sc1"
                             : "=&v"(af[kk]) : "v"(pl + kk * 1024) : "memory");
        }
        asm volatile("s_waitcnt vmcnt(0)" ::: "memory");
        __builtin_amdgcn_sched_barrier(0);   // rule 18

        // ---- 32 Wh-MFMAs (regs) + 16 Wx-MFMAs (B from LDS) ----
        f32x4_t acc[4];
        #pragma unroll
        for (int nt = 0; nt < 4; ++nt) acc[nt] = f32x4_t{0.f, 0.f, 0.f, 0.f};
        #pragma unroll
        for (int kk = 0; kk < 8; ++kk) {
            #pragma unroll
            for (int nt = 0; nt < 4; ++nt)
                acc[nt] = mfma16(af[kk], bf[nt][kk], acc[nt]);
        }
        #pragma unroll
        for (int kk = 0; kk < 4; ++kk) {
            #pragma unroll
            for (int nt = 0; nt < 4; ++nt) {
                f16x8 wb = *(const f16x8*)(wx + (((((w * 4 + kk) * 4) + nt) * 64 + l) << 3));
                acc[nt] = mfma16(xa[kk], wb, acc[nt]);
            }
        }

        // ---- cross-wave K-reduction via LDS ----
        {
            const int r0 = dh << 2;
            #pragma unroll
            for (int nt = 0; nt < 4; ++nt)
                #pragma unroll
                for (int j = 0; j < 4; ++j)
                    pacc[w][nt][r0 + j][l & 15] = acc[nt][j];
        }
        lds_barrier();

        float g0 = pacc[0][w][lb][0 * 4 + dh] + pacc[1][w][lb][0 * 4 + dh]
                 + pacc[2][w][lb][0 * 4 + dh] + pacc[3][w][lb][0 * 4 + dh] + b0;
        float g1 = pacc[0][w][lb][1 * 4 + dh] + pacc[1][w][lb][1 * 4 + dh]
                 + pacc[2][w][lb][1 * 4 + dh] + pacc[3][w][lb][1 * 4 + dh] + b1;
        float g2 = pacc[0][w][lb][2 * 4 + dh] + pacc[1][w][lb][2 * 4 + dh]
                 + pacc[2][w][lb][2 * 4 + dh] + pacc[3][w][lb][2 * 4 + dh] + b2;
        float g3 = pacc[0][w][lb][3 * 4 + dh] + pacc[1][w][lb][3 * 4 + dh]
                 + pacc[2][w][lb][3 * 4 + dh] + pacc[3][w][lb][3 * 4 + dh] + b3;

        float si = fsig(g0);
        float tj = ftanh(g1);
        float sf = fsig(g2 + 1.f);
        float so = fsig(g3);
        cst = cst * sf + si * tj;
        float h = ftanh(cst) * so;

        // ---- publish: payload stores -> wave ack -> wave tag ----
        {
            unsigned hu = (unsigned)__builtin_bit_cast(unsigned short, (f16)h);
            unsigned ot = __shfl_xor(hu, 16);
            unsigned dw = (dh & 1) ? ((ot & 0xffffu) | (hu << 16))
                                   : ((hu & 0xffffu) | (ot << 16));
            unsigned dw2 = __shfl_xor(dw, 32);
            if (do_st && t < T_ - 1) {
                u64 val = (u64)dw | ((u64)dw2 << 32);
                __hip_atomic_store((u64*)(pay + (size_t)nxt * PAYB + st_off), val,
                                   __ATOMIC_RELAXED, __HIP_MEMORY_SCOPE_AGENT);
            }
        }
        asm volatile("s_waitcnt vmcnt(0)" ::: "memory");
        if (l == 0 && t < T_ - 1)
            __hip_atomic_store(tag_st, (unsigned)(t + 2),
                               __ATOMIC_RELAXED, __HIP_MEMORY_SCOPE_AGENT);

        // ---- x-fragment prefetch for t+1 (plain cached; rides the poll) ----
        if (t + 1 < T_) {
            const f16* pn = xf + (size_t)(t + 1) * 32768 + (size_t)bg * 8192
                          + ((size_t)(w * 4) * 64 + l) * 8;
            #pragma unroll
            for (int kk = 0; kk < 4; ++kk)
                xa[kk] = *(const f16x8*)(pn + (size_t)kk * 512);
        }

        h_prev = h;
        oprev  = ((size_t)bglob * T_ + t) * N_ + nh;

        lds_barrier();   // pacc anti-dependency
        cur = nxt;
        nxt = (nxt == 2) ? 0 : nxt + 1;
    }
    __builtin_nontemporal_store(h_prev, &out[oprev]);
}

// ---------------------------------------------------------------------------
extern "C" void kernel_launch(void* const* d_in, const int* in_sizes, int n_in,
                              void* d_out, int out_size, void* d_ws, size_t ws_size,
                              hipStream_t stream) {
    const float* x    = (const float*)d_in[0];
    const float* W    = (const float*)d_in[1];
    const float* bias = (const float*)d_in[2];
    float* out = (float*)d_out;

    char* ws = (char*)d_ws;
    f16*  xf = (f16*)(ws + OFF_XF);   // 32 MB of x fragments

    const size_t need = OFF_XF + (size_t)T_ * 32768 * sizeof(f16);
    if (ws_size < need) {
        hipMemsetAsync(d_out, 0, (size_t)out_size * sizeof(float), stream);
        return;
    }

    hipLaunchKernelGGL(k_xfrag, dim3(512), dim3(256), 0, stream, x, xf);

    // tag reset: re-executes on every graph replay -> deterministic start
    hipMemsetAsync(ws + OFF_TAG, 0, 4096, stream);

    void* args[] = { (void*)&W, (void*)&bias, (void*)&xf, (void*)&ws, (void*)&out };
    hipError_t e = hipLaunchCooperativeKernel((void*)k_recur15, dim3(256), dim3(256),
                                              args, 0, stream);
    if (e != hipSuccess) {
        // ~84KB LDS -> 1 WG/CU, grid 256 == CU count: co-residency holds
        hipLaunchKernelGGL(k_recur15, dim3(256), dim3(256), 0, stream,
                           W, bias, xf, ws, out);
    }
}

// Round 16
// 1574.239 us; speedup vs baseline: 1.4335x; 1.0493x over previous
//
#include <hip/hip_runtime.h>

#define B_ 64
#define T_ 512
#define D_ 512
#define N_ 1024
#define G_ 4096   // 4*N

typedef _Float16 f16;
typedef __attribute__((ext_vector_type(8))) _Float16 f16x8;
typedef __attribute__((ext_vector_type(4))) float f32x4_t;
typedef unsigned long long u64;

static __device__ __forceinline__ f32x4_t mfma16(f16x8 a, f16x8 b, f32x4_t c) {
    return __builtin_amdgcn_mfma_f32_16x16x32_f16(a, b, c, 0, 0, 0);
}

static __device__ __forceinline__ float fsig(float x) {
    return 1.f / (1.f + __expf(-x));
}
static __device__ __forceinline__ float ftanh(float x) {
    return 1.f - 2.f / (__expf(2.f * x) + 1.f);
}

static __device__ __forceinline__ void lds_barrier() {
    asm volatile("s_waitcnt lgkmcnt(0)" ::: "memory");
    __builtin_amdgcn_s_barrier();
    __builtin_amdgcn_sched_barrier(0);
}

// workspace map: [0,4MB) protocol region; [4MB, +32MB) x-fragments
#define PAYB   131072        // one payload copy: [bg4][32KB]
#define OFF_TAG 0x60000      // 3*PAYB; tags: [bg4][rep8][256] u32 = 32KB
#define OFF_XF  ((size_t)4 << 20)

// ---------------------------------------------------------------------------
// Phase 0: x -> f16 MFMA A-fragments (validated R15)
// ---------------------------------------------------------------------------
__global__ __launch_bounds__(256) void k_xfrag(const float* __restrict__ x,
                                               f16* __restrict__ xf) {
    __shared__ __align__(16) f16 xl[32768];   // 64 KB
    const int t = blockIdx.x;
    const int tid = threadIdx.x;

    for (int ch = tid; ch < 4096; ch += 256) {
        int b  = ch >> 6;
        int d0 = (ch & 63) << 3;
        const float* px = x + ((size_t)b * T_ + t) * D_ + d0;
        float4 v0 = *(const float4*)px;
        float4 v1 = *(const float4*)(px + 4);
        f16x8 s;
        s[0] = (f16)v0.x; s[1] = (f16)v0.y; s[2] = (f16)v0.z; s[3] = (f16)v0.w;
        s[4] = (f16)v1.x; s[5] = (f16)v1.y; s[6] = (f16)v1.z; s[7] = (f16)v1.w;
        int bg = b >> 4, ds = d0 >> 5;
        int lane = (((d0 >> 3) & 3) << 4) | (b & 15);
        *(f16x8*)(xl + (((bg * 16 + ds) * 64 + lane) << 3)) = s;
    }
    __syncthreads();
    f16* dst = xf + (size_t)t * 32768;
    for (int j = tid; j < 4096; j += 256)
        *(f16x8*)(dst + j * 8) = *(const f16x8*)(xl + j * 8);
}

// ---------------------------------------------------------------------------
// Phase 1: persistent recurrence (R15 structure, validated 1.65ms total).
// R16 delta: TAG REPLICATION x8 — producer wave stores its tag to 8 replica
// lines (lanes 0-7, one ack shared with payload); consumer WG ci polls
// replica (ci&7) -> per-line poll contention drops 64 -> 8 readers.
// ---------------------------------------------------------------------------
__global__ __launch_bounds__(256, 1) void k_recur16(const float* __restrict__ W,
                                                    const float* __restrict__ bias,
                                                    const f16* __restrict__ xf,
                                                    char* __restrict__ wsb,
                                                    float* __restrict__ out) {
    __shared__ __align__(16) f16 wx[32768];     // 64 KB Wx B-fragments
    __shared__ float pacc[4][4][16][17];        // 17.4 KB

    const int wg  = blockIdx.x;
    const int tid = threadIdx.x;
    const int w   = tid >> 6;
    const int l   = tid & 63;
    const int bg  = wg >> 6;
    const int ci  = wg & 63;

    const int lb    = l & 15;
    const int dh    = l >> 4;
    const int nh    = ci * 16 + w * 4 + dh;
    const int bglob = bg * 16 + lb;

    char*     const pay  = wsb;
    unsigned* const tags = (unsigned*)(wsb + OFF_TAG);   // [bg][rep8][256]

    // ---- Wh B-fragments into registers (validated R3/R9/R10) ----
    f16x8 bf[4][8];
    {
        const int kq = l >> 4, ty = (l >> 2) & 3, dcl = l & 3;
        #pragma unroll
        for (int nt = 0; nt < 4; ++nt) {
            const int gc = ty * 1024 + ci * 16 + nt * 4 + dcl;
            #pragma unroll
            for (int kk = 0; kk < 8; ++kk) {
                #pragma unroll
                for (int i = 0; i < 8; ++i) {
                    int k = (w * 8 + kk) * 32 + kq * 8 + i;
                    bf[nt][kk][i] = (f16)W[(size_t)(D_ + k) * G_ + gc];
                }
            }
        }
    }

    // ---- Wx B-fragments into LDS (validated R15) ----
    for (int idx = tid; idx < 32768; idx += 256) {
        int gcl = idx & 63;
        int d   = idx >> 6;
        int ty  = gcl >> 4, c = gcl & 15;
        float wv = W[(size_t)d * G_ + ty * 1024 + ci * 16 + c];
        int ds = d >> 5, i = d & 7, kq = (d >> 3) & 3;
        int nt = c >> 2, dcl = c & 3;
        int lane = (kq << 4) | (ty << 2) | dcl;
        wx[(((ds * 4 + nt) * 64 + lane) << 3) + i] = (f16)wv;
    }

    // bias for this thread's 4 gates
    const float b0 = bias[0 * 1024 + nh];
    const float b1 = bias[1 * 1024 + nh];
    const float b2 = bias[2 * 1024 + nh];
    const float b3 = bias[3 * 1024 + nh];

    // ---- producer/consumer addressing (R8/R10-validated) ----
    const int nq  = ci * 16 + w * 4;
    const int ksq = nq >> 5;
    const int q8  = (nq & 31) >> 3;
    const size_t st_off = (size_t)bg * 32768
                        + ((size_t)(ksq * 64 + q8 * 16 + lb) << 4)
                        + (size_t)(w & 1) * 8;
    const bool do_st = (dh == 0);
    const size_t ld_off = (size_t)bg * 32768 + ((size_t)(w * 8 * 64 + l) << 4);

    // tags: producer (ci,w) writes 8 replicas (lane r<8 -> replica r);
    // consumer WG ci reads replica ci&7.
    unsigned* const tag_st = tags + (bg * 2048 + l * 256 + ci * 4 + w);  // l<8
    unsigned* const tag_ld = tags + (bg * 2048 + (ci & 7) * 256 + w * 64 + l);

    // ---- init: zero payload buf0 (h_0 = 0), release, tags = 1 ----
    if (do_st)
        __hip_atomic_store((u64*)(pay + st_off), 0ull,
                           __ATOMIC_RELAXED, __HIP_MEMORY_SCOPE_AGENT);
    asm volatile("s_waitcnt vmcnt(0)" ::: "memory");
    if (l < 8)
        __hip_atomic_store(tag_st, 1u, __ATOMIC_RELAXED, __HIP_MEMORY_SCOPE_AGENT);

    __syncthreads();   // also covers wx staging

    // prologue: x-fragments for t=0
    f16x8 xa[4];
    {
        const f16* p0 = xf + (size_t)bg * 8192 + ((size_t)(w * 4) * 64 + l) * 8;
        #pragma unroll
        for (int kk = 0; kk < 4; ++kk)
            xa[kk] = *(const f16x8*)(p0 + (size_t)kk * 512);
    }

    float cst = 0.f;
    int cur = 0, nxt = 1;
    float  h_prev = 0.f;
    size_t oprev  = 0;

    for (int t = 0; t < T_; ++t) {
        if (t > 0)
            __builtin_nontemporal_store(h_prev, &out[oprev]);

        // ---- poll own 64 producer-wave tags (replica ci&7) ----
        {
            const unsigned tgt = (unsigned)(t + 1);
            while (true) {
                unsigned v = __hip_atomic_load(tag_ld, __ATOMIC_RELAXED,
                                               __HIP_MEMORY_SCOPE_AGENT);
                if (__all(v >= tgt)) break;
                __builtin_amdgcn_s_sleep(1);
            }
        }

        // ---- payload: 8 x 16B coherent loads ----
        f16x8 af[8];
        {
            const char* pl = pay + (size_t)cur * PAYB + ld_off;
            #pragma unroll
            for (int kk = 0; kk < 8; ++kk)
                asm volatile("global_load_dwordx4 %0, %1, off sc0 sc1"
                             : "=&v"(af[kk]) : "v"(pl + kk * 1024) : "memory");
        }
        asm volatile("s_waitcnt vmcnt(0)" ::: "memory");
        __builtin_amdgcn_sched_barrier(0);   // rule 18

        // ---- 32 Wh-MFMAs (regs) + 16 Wx-MFMAs (B from LDS) ----
        f32x4_t acc[4];
        #pragma unroll
        for (int nt = 0; nt < 4; ++nt) acc[nt] = f32x4_t{0.f, 0.f, 0.f, 0.f};
        #pragma unroll
        for (int kk = 0; kk < 8; ++kk) {
            #pragma unroll
            for (int nt = 0; nt < 4; ++nt)
                acc[nt] = mfma16(af[kk], bf[nt][kk], acc[nt]);
        }
        #pragma unroll
        for (int kk = 0; kk < 4; ++kk) {
            #pragma unroll
            for (int nt = 0; nt < 4; ++nt) {
                f16x8 wb = *(const f16x8*)(wx + (((((w * 4 + kk) * 4) + nt) * 64 + l) << 3));
                acc[nt] = mfma16(xa[kk], wb, acc[nt]);
            }
        }

        // ---- cross-wave K-reduction via LDS ----
        {
            const int r0 = dh << 2;
            #pragma unroll
            for (int nt = 0; nt < 4; ++nt)
                #pragma unroll
                for (int j = 0; j < 4; ++j)
                    pacc[w][nt][r0 + j][l & 15] = acc[nt][j];
        }
        lds_barrier();

        float g0 = pacc[0][w][lb][0 * 4 + dh] + pacc[1][w][lb][0 * 4 + dh]
                 + pacc[2][w][lb][0 * 4 + dh] + pacc[3][w][lb][0 * 4 + dh] + b0;
        float g1 = pacc[0][w][lb][1 * 4 + dh] + pacc[1][w][lb][1 * 4 + dh]
                 + pacc[2][w][lb][1 * 4 + dh] + pacc[3][w][lb][1 * 4 + dh] + b1;
        float g2 = pacc[0][w][lb][2 * 4 + dh] + pacc[1][w][lb][2 * 4 + dh]
                 + pacc[2][w][lb][2 * 4 + dh] + pacc[3][w][lb][2 * 4 + dh] + b2;
        float g3 = pacc[0][w][lb][3 * 4 + dh] + pacc[1][w][lb][3 * 4 + dh]
                 + pacc[2][w][lb][3 * 4 + dh] + pacc[3][w][lb][3 * 4 + dh] + b3;

        float si = fsig(g0);
        float tj = ftanh(g1);
        float sf = fsig(g2 + 1.f);
        float so = fsig(g3);
        cst = cst * sf + si * tj;
        float h = ftanh(cst) * so;

        // ---- publish: payload stores -> wave ack -> 8 replica tags ----
        {
            unsigned hu = (unsigned)__builtin_bit_cast(unsigned short, (f16)h);
            unsigned ot = __shfl_xor(hu, 16);
            unsigned dw = (dh & 1) ? ((ot & 0xffffu) | (hu << 16))
                                   : ((hu & 0xffffu) | (ot << 16));
            unsigned dw2 = __shfl_xor(dw, 32);
            if (do_st && t < T_ - 1) {
                u64 val = (u64)dw | ((u64)dw2 << 32);
                __hip_atomic_store((u64*)(pay + (size_t)nxt * PAYB + st_off), val,
                                   __ATOMIC_RELAXED, __HIP_MEMORY_SCOPE_AGENT);
            }
        }
        asm volatile("s_waitcnt vmcnt(0)" ::: "memory");   // payload acked at LLC
        if (l < 8 && t < T_ - 1)
            __hip_atomic_store(tag_st, (unsigned)(t + 2),
                               __ATOMIC_RELAXED, __HIP_MEMORY_SCOPE_AGENT);

        // ---- x-fragment prefetch for t+1 (plain cached; rides the poll) ----
        if (t + 1 < T_) {
            const f16* pn = xf + (size_t)(t + 1) * 32768 + (size_t)bg * 8192
                          + ((size_t)(w * 4) * 64 + l) * 8;
            #pragma unroll
            for (int kk = 0; kk < 4; ++kk)
                xa[kk] = *(const f16x8*)(pn + (size_t)kk * 512);
        }

        h_prev = h;
        oprev  = ((size_t)bglob * T_ + t) * N_ + nh;

        lds_barrier();   // pacc anti-dependency
        cur = nxt;
        nxt = (nxt == 2) ? 0 : nxt + 1;
    }
    __builtin_nontemporal_store(h_prev, &out[oprev]);
}

// ---------------------------------------------------------------------------
extern "C" void kernel_launch(void* const* d_in, const int* in_sizes, int n_in,
                              void* d_out, int out_size, void* d_ws, size_t ws_size,
                              hipStream_t stream) {
    const float* x    = (const float*)d_in[0];
    const float* W    = (const float*)d_in[1];
    const float* bias = (const float*)d_in[2];
    float* out = (float*)d_out;

    char* ws = (char*)d_ws;
    f16*  xf = (f16*)(ws + OFF_XF);   // 32 MB of x fragments

    const size_t need = OFF_XF + (size_t)T_ * 32768 * sizeof(f16);
    if (ws_size < need) {
        hipMemsetAsync(d_out, 0, (size_t)out_size * sizeof(float), stream);
        return;
    }

    hipLaunchKernelGGL(k_xfrag, dim3(512), dim3(256), 0, stream, x, xf);

    // tag reset (now 32KB: 8 replicas); re-executes on every graph replay.
    // Kernel-boundary L2 writeback makes the memset visible to sc0sc1 readers.
    hipMemsetAsync(ws + OFF_TAG, 0, 32768, stream);

    void* args[] = { (void*)&W, (void*)&bias, (void*)&xf, (void*)&ws, (void*)&out };
    hipError_t e = hipLaunchCooperativeKernel((void*)k_recur16, dim3(256), dim3(256),
                                              args, 0, stream);
    if (e != hipSuccess) {
        // ~84KB LDS -> 1 WG/CU, grid 256 == CU count: co-residency holds
        hipLaunchKernelGGL(k_recur16, dim3(256), dim3(256), 0, stream,
                           W, bias, xf, ws, out);
    }
}

// Round 17
// 1502.498 us; speedup vs baseline: 1.5019x; 1.0477x over previous
//
#include <hip/hip_runtime.h>

#define B_ 64
#define T_ 512
#define D_ 512
#define N_ 1024
#define G_ 4096   // 4*N

typedef _Float16 f16;
typedef __attribute__((ext_vector_type(8))) _Float16 f16x8;
typedef __attribute__((ext_vector_type(4))) float f32x4_t;
typedef unsigned long long u64;

static __device__ __forceinline__ f32x4_t mfma16(f16x8 a, f16x8 b, f32x4_t c) {
    return __builtin_amdgcn_mfma_f32_16x16x32_f16(a, b, c, 0, 0, 0);
}

static __device__ __forceinline__ float fsig(float x) {
    return 1.f / (1.f + __expf(-x));
}
static __device__ __forceinline__ float ftanh(float x) {
    return 1.f - 2.f / (__expf(2.f * x) + 1.f);
}

static __device__ __forceinline__ void lds_barrier() {
    asm volatile("s_waitcnt lgkmcnt(0)" ::: "memory");
    __builtin_amdgcn_s_barrier();
    __builtin_amdgcn_sched_barrier(0);
}

// workspace map: payload 4 replicas x 3 bufs x 128KB = 1.5MB; tags 32KB; xf.
#define PAYB    131072         // one payload buffer copy: [bg4][32KB]
#define REPS    0x60000        // replica stride = 3*PAYB
#define OFF_TAG 0x180000       // tags: [bg4][rep8][256] u32 = 32KB
#define OFF_XF  ((size_t)4 << 20)

// ---------------------------------------------------------------------------
// Phase 0: x -> f16 MFMA A-fragments (validated R15)
// ---------------------------------------------------------------------------
__global__ __launch_bounds__(256) void k_xfrag(const float* __restrict__ x,
                                               f16* __restrict__ xf) {
    __shared__ __align__(16) f16 xl[32768];   // 64 KB
    const int t = blockIdx.x;
    const int tid = threadIdx.x;

    for (int ch = tid; ch < 4096; ch += 256) {
        int b  = ch >> 6;
        int d0 = (ch & 63) << 3;
        const float* px = x + ((size_t)b * T_ + t) * D_ + d0;
        float4 v0 = *(const float4*)px;
        float4 v1 = *(const float4*)(px + 4);
        f16x8 s;
        s[0] = (f16)v0.x; s[1] = (f16)v0.y; s[2] = (f16)v0.z; s[3] = (f16)v0.w;
        s[4] = (f16)v1.x; s[5] = (f16)v1.y; s[6] = (f16)v1.z; s[7] = (f16)v1.w;
        int bg = b >> 4, ds = d0 >> 5;
        int lane = (((d0 >> 3) & 3) << 4) | (b & 15);
        *(f16x8*)(xl + (((bg * 16 + ds) * 64 + lane) << 3)) = s;
    }
    __syncthreads();
    f16* dst = xf + (size_t)t * 32768;
    for (int j = tid; j < 4096; j += 256)
        *(f16x8*)(dst + j * 8) = *(const f16x8*)(xl + j * 8);
}

// ---------------------------------------------------------------------------
// Phase 1: persistent recurrence (R16 structure, validated 1.57ms total).
// R17 deltas:
//  (a) PAYLOAD REPLICATION x4 — producer dh==0 lanes store their 8B slot to
//      4 replica regions (one shared ack); consumer WG reads replica ci&3
//      -> per-line reader fan-out 64 -> 16 (same mechanics as R16's tag fix).
//  (b) Wx-MFMA block HOISTED before the tag poll — depends only on prefetched
//      xa + static LDS, so it runs in the poll's shadow; the serial region
//      after payload arrival shrinks to the 32 Wh-MFMAs.
// ---------------------------------------------------------------------------
__global__ __launch_bounds__(256, 1) void k_recur17(const float* __restrict__ W,
                                                    const float* __restrict__ bias,
                                                    const f16* __restrict__ xf,
                                                    char* __restrict__ wsb,
                                                    float* __restrict__ out) {
    __shared__ __align__(16) f16 wx[32768];     // 64 KB Wx B-fragments
    __shared__ float pacc[4][4][16][17];        // 17.4 KB

    const int wg  = blockIdx.x;
    const int tid = threadIdx.x;
    const int w   = tid >> 6;
    const int l   = tid & 63;
    const int bg  = wg >> 6;
    const int ci  = wg & 63;

    const int lb    = l & 15;
    const int dh    = l >> 4;
    const int nh    = ci * 16 + w * 4 + dh;
    const int bglob = bg * 16 + lb;

    unsigned* const tags = (unsigned*)(wsb + OFF_TAG);   // [bg][rep8][256]

    // ---- Wh B-fragments into registers (validated R3/R9/R10) ----
    f16x8 bf[4][8];
    {
        const int kq = l >> 4, ty = (l >> 2) & 3, dcl = l & 3;
        #pragma unroll
        for (int nt = 0; nt < 4; ++nt) {
            const int gc = ty * 1024 + ci * 16 + nt * 4 + dcl;
            #pragma unroll
            for (int kk = 0; kk < 8; ++kk) {
                #pragma unroll
                for (int i = 0; i < 8; ++i) {
                    int k = (w * 8 + kk) * 32 + kq * 8 + i;
                    bf[nt][kk][i] = (f16)W[(size_t)(D_ + k) * G_ + gc];
                }
            }
        }
    }

    // ---- Wx B-fragments into LDS (validated R15) ----
    for (int idx = tid; idx < 32768; idx += 256) {
        int gcl = idx & 63;
        int d   = idx >> 6;
        int ty  = gcl >> 4, c = gcl & 15;
        float wv = W[(size_t)d * G_ + ty * 1024 + ci * 16 + c];
        int ds = d >> 5, i = d & 7, kq = (d >> 3) & 3;
        int nt = c >> 2, dcl = c & 3;
        int lane = (kq << 4) | (ty << 2) | dcl;
        wx[(((ds * 4 + nt) * 64 + lane) << 3) + i] = (f16)wv;
    }

    const float b0 = bias[0 * 1024 + nh];
    const float b1 = bias[1 * 1024 + nh];
    const float b2 = bias[2 * 1024 + nh];
    const float b3 = bias[3 * 1024 + nh];

    // ---- producer/consumer addressing (R8/R10-validated slot layout) ----
    const int nq  = ci * 16 + w * 4;
    const int ksq = nq >> 5;
    const int q8  = (nq & 31) >> 3;
    const size_t st_off = (size_t)bg * 32768
                        + ((size_t)(ksq * 64 + q8 * 16 + lb) << 4)
                        + (size_t)(w & 1) * 8;
    const bool do_st = (dh == 0);
    const size_t ld_off = (size_t)bg * 32768 + ((size_t)(w * 8 * 64 + l) << 4);
    char* const myrep = wsb + (size_t)(ci & 3) * REPS;   // consumer replica

    // tags: producer (ci,w) writes 8 replicas (lanes 0-7); consumer reads ci&7
    unsigned* const tag_st = tags + (bg * 2048 + l * 256 + ci * 4 + w);  // l<8
    unsigned* const tag_ld = tags + (bg * 2048 + (ci & 7) * 256 + w * 64 + l);

    // ---- init: zero payload buf0 in all 4 replicas, release, tags = 1 ----
    if (do_st) {
        #pragma unroll
        for (int r = 0; r < 4; ++r)
            __hip_atomic_store((u64*)(wsb + (size_t)r * REPS + st_off), 0ull,
                               __ATOMIC_RELAXED, __HIP_MEMORY_SCOPE_AGENT);
    }
    asm volatile("s_waitcnt vmcnt(0)" ::: "memory");
    if (l < 8)
        __hip_atomic_store(tag_st, 1u, __ATOMIC_RELAXED, __HIP_MEMORY_SCOPE_AGENT);

    __syncthreads();   // also covers wx staging

    // prologue: x-fragments for t=0
    f16x8 xa[4];
    {
        const f16* p0 = xf + (size_t)bg * 8192 + ((size_t)(w * 4) * 64 + l) * 8;
        #pragma unroll
        for (int kk = 0; kk < 4; ++kk)
            xa[kk] = *(const f16x8*)(p0 + (size_t)kk * 512);
    }

    float cst = 0.f;
    int cur = 0, nxt = 1;
    float  h_prev = 0.f;
    size_t oprev  = 0;

    for (int t = 0; t < T_; ++t) {
        if (t > 0)
            __builtin_nontemporal_store(h_prev, &out[oprev]);

        // ---- (b) Wx-MFMAs hoisted: run in the poll's shadow ----
        f32x4_t acc[4];
        #pragma unroll
        for (int nt = 0; nt < 4; ++nt) acc[nt] = f32x4_t{0.f, 0.f, 0.f, 0.f};
        #pragma unroll
        for (int kk = 0; kk < 4; ++kk) {
            #pragma unroll
            for (int nt = 0; nt < 4; ++nt) {
                f16x8 wb = *(const f16x8*)(wx + (((((w * 4 + kk) * 4) + nt) * 64 + l) << 3));
                acc[nt] = mfma16(xa[kk], wb, acc[nt]);
            }
        }

        // ---- poll own 64 producer-wave tags (replica ci&7) ----
        {
            const unsigned tgt = (unsigned)(t + 1);
            while (true) {
                unsigned v = __hip_atomic_load(tag_ld, __ATOMIC_RELAXED,
                                               __HIP_MEMORY_SCOPE_AGENT);
                if (__all(v >= tgt)) break;
                __builtin_amdgcn_s_sleep(1);
            }
        }

        // ---- payload: 8 x 16B coherent loads from replica ci&3 ----
        f16x8 af[8];
        {
            const char* pl = myrep + (size_t)cur * PAYB + ld_off;
            #pragma unroll
            for (int kk = 0; kk < 8; ++kk)
                asm volatile("global_load_dwordx4 %0, %1, off sc0 sc1"
                             : "=&v"(af[kk]) : "v"(pl + kk * 1024) : "memory");
        }
        asm volatile("s_waitcnt vmcnt(0)" ::: "memory");
        __builtin_amdgcn_sched_barrier(0);   // rule 18

        // ---- 32 Wh-MFMAs (B in regs) ----
        #pragma unroll
        for (int kk = 0; kk < 8; ++kk) {
            #pragma unroll
            for (int nt = 0; nt < 4; ++nt)
                acc[nt] = mfma16(af[kk], bf[nt][kk], acc[nt]);
        }

        // ---- cross-wave K-reduction via LDS ----
        {
            const int r0 = dh << 2;
            #pragma unroll
            for (int nt = 0; nt < 4; ++nt)
                #pragma unroll
                for (int j = 0; j < 4; ++j)
                    pacc[w][nt][r0 + j][l & 15] = acc[nt][j];
        }
        lds_barrier();

        float g0 = pacc[0][w][lb][0 * 4 + dh] + pacc[1][w][lb][0 * 4 + dh]
                 + pacc[2][w][lb][0 * 4 + dh] + pacc[3][w][lb][0 * 4 + dh] + b0;
        float g1 = pacc[0][w][lb][1 * 4 + dh] + pacc[1][w][lb][1 * 4 + dh]
                 + pacc[2][w][lb][1 * 4 + dh] + pacc[3][w][lb][1 * 4 + dh] + b1;
        float g2 = pacc[0][w][lb][2 * 4 + dh] + pacc[1][w][lb][2 * 4 + dh]
                 + pacc[2][w][lb][2 * 4 + dh] + pacc[3][w][lb][2 * 4 + dh] + b2;
        float g3 = pacc[0][w][lb][3 * 4 + dh] + pacc[1][w][lb][3 * 4 + dh]
                 + pacc[2][w][lb][3 * 4 + dh] + pacc[3][w][lb][3 * 4 + dh] + b3;

        float si = fsig(g0);
        float tj = ftanh(g1);
        float sf = fsig(g2 + 1.f);
        float so = fsig(g3);
        cst = cst * sf + si * tj;
        float h = ftanh(cst) * so;

        // ---- publish: 4 replica payload stores -> one ack -> 8 tag stores ----
        {
            unsigned hu = (unsigned)__builtin_bit_cast(unsigned short, (f16)h);
            unsigned ot = __shfl_xor(hu, 16);
            unsigned dw = (dh & 1) ? ((ot & 0xffffu) | (hu << 16))
                                   : ((hu & 0xffffu) | (ot << 16));
            unsigned dw2 = __shfl_xor(dw, 32);
            if (do_st && t < T_ - 1) {
                u64 val = (u64)dw | ((u64)dw2 << 32);
                #pragma unroll
                for (int r = 0; r < 4; ++r)
                    __hip_atomic_store(
                        (u64*)(wsb + (size_t)r * REPS + (size_t)nxt * PAYB + st_off),
                        val, __ATOMIC_RELAXED, __HIP_MEMORY_SCOPE_AGENT);
            }
        }
        asm volatile("s_waitcnt vmcnt(0)" ::: "memory");   // payload acked at LLC
        if (l < 8 && t < T_ - 1)
            __hip_atomic_store(tag_st, (unsigned)(t + 2),
                               __ATOMIC_RELAXED, __HIP_MEMORY_SCOPE_AGENT);

        // ---- x-fragment prefetch for t+1 (plain cached; rides the poll) ----
        if (t + 1 < T_) {
            const f16* pn = xf + (size_t)(t + 1) * 32768 + (size_t)bg * 8192
                          + ((size_t)(w * 4) * 64 + l) * 8;
            #pragma unroll
            for (int kk = 0; kk < 4; ++kk)
                xa[kk] = *(const f16x8*)(pn + (size_t)kk * 512);
        }

        h_prev = h;
        oprev  = ((size_t)bglob * T_ + t) * N_ + nh;

        lds_barrier();   // pacc anti-dependency
        cur = nxt;
        nxt = (nxt == 2) ? 0 : nxt + 1;
    }
    __builtin_nontemporal_store(h_prev, &out[oprev]);
}

// ---------------------------------------------------------------------------
extern "C" void kernel_launch(void* const* d_in, const int* in_sizes, int n_in,
                              void* d_out, int out_size, void* d_ws, size_t ws_size,
                              hipStream_t stream) {
    const float* x    = (const float*)d_in[0];
    const float* W    = (const float*)d_in[1];
    const float* bias = (const float*)d_in[2];
    float* out = (float*)d_out;

    char* ws = (char*)d_ws;
    f16*  xf = (f16*)(ws + OFF_XF);   // 32 MB of x fragments

    const size_t need = OFF_XF + (size_t)T_ * 32768 * sizeof(f16);
    if (ws_size < need) {
        hipMemsetAsync(d_out, 0, (size_t)out_size * sizeof(float), stream);
        return;
    }

    hipLaunchKernelGGL(k_xfrag, dim3(512), dim3(256), 0, stream, x, xf);

    // tag reset; re-executes on every graph replay -> deterministic start.
    hipMemsetAsync(ws + OFF_TAG, 0, 32768, stream);

    void* args[] = { (void*)&W, (void*)&bias, (void*)&xf, (void*)&ws, (void*)&out };
    hipError_t e = hipLaunchCooperativeKernel((void*)k_recur17, dim3(256), dim3(256),
                                              args, 0, stream);
    if (e != hipSuccess) {
        // ~84KB LDS -> 1 WG/CU, grid 256 == CU count: co-residency holds
        hipLaunchKernelGGL(k_recur17, dim3(256), dim3(256), 0, stream,
                           W, bias, xf, ws, out);
    }
}